// Round 5
// baseline (989.622 us; speedup 1.0000x reference)
//
#include <hip/hip_runtime.h>

__device__ __forceinline__ float sigf(float x){ return 1.0f/(1.0f+__expf(-x)); }
__device__ __forceinline__ float tanhfast(float x){ return 1.0f - 2.0f/(__expf(2.0f*x)+1.0f); }
__device__ __forceinline__ float rlane(float v, int l){
  return __uint_as_float(__builtin_amdgcn_readlane(__float_as_uint(v), l));
}

#define Bn 16
#define Tn 128
#define Fn 40
#define Hn 64
#define Dn 80   // 2F
#define NHn 5
#define DKn 16
#define FFn 320

// ---------------- Stage A: per-feature LSTMs, wave-per-instance, no barriers ----------------
// grid 1290 x 64 threads. blk<640: q-LSTM inst=blk; 640<=blk<1280: k-LSTM; blk>=1280: v-LSTM lane-parallel.
// Lane l owns h[l],c[l]; gates {l,64+l,128+l,192+l}; h broadcast via v_readlane.
__global__ __launch_bounds__(64,1) void k_feat_lstm_w(
    const float* __restrict__ x,
    const float* __restrict__ qWih, const float* __restrict__ qWhh, const float* __restrict__ qb,
    const float* __restrict__ kWih, const float* __restrict__ kWhh, const float* __restrict__ kb,
    const float* __restrict__ vWih, const float* __restrict__ vWhh, const float* __restrict__ vb,
    float* __restrict__ hq, float* __restrict__ hk, float* __restrict__ hv)
{
  const int blk = blockIdx.x;
  const int l = threadIdx.x;
  if (blk >= 1280){
    const int inst = (blk - 1280)*64 + l;       // 0..639
    const int bi = inst/Fn, f = inst%Fn;
    const float* xp = x + bi*Tn*Fn + f;
    const float wih0=vWih[0], wih1=vWih[1], wih2=vWih[2], wih3=vWih[3];
    const float u0=vWhh[0], u1=vWhh[1], u2=vWhh[2], u3=vWhh[3];
    const float c0=vb[0], c1=vb[1], c2=vb[2], c3=vb[3];
    float h=0.f, c=0.f;
    #pragma unroll 1
    for (int t=0;t<Tn;++t){
      float xt = xp[t*Fn];
      float zi = xt*wih0 + h*u0 + c0;
      float zf = xt*wih1 + h*u1 + c1;
      float zg = xt*wih2 + h*u2 + c2;
      float zo = xt*wih3 + h*u3 + c3;
      c = sigf(zf)*c + sigf(zi)*tanhfast(zg);
      h = sigf(zo)*tanhfast(c);
    }
    hv[inst] = h;
    return;
  }
  const bool isk = blk >= 640;
  const int inst = isk ? blk-640 : blk;         // 0..639
  const int bi = inst/Fn, f = inst%Fn;
  const float* Whh = isk ? kWhh : qWhh;
  const float* Wih = isk ? kWih : qWih;
  const float* bia = isk ? kb  : qb;
  float* outp = isk ? hk : hq;

  // Whh rows for this lane's 4 gates -> 256 VGPRs (launch_bounds(64,1) => 512 budget)
  float w0[Hn], w1[Hn], w2[Hn], w3[Hn];
  {
    const float* r0 = Whh + (0*Hn + l)*Hn;
    const float* r1 = Whh + (1*Hn + l)*Hn;
    const float* r2 = Whh + (2*Hn + l)*Hn;
    const float* r3 = Whh + (3*Hn + l)*Hn;
    #pragma unroll
    for (int j=0;j<Hn;j+=4){
      float4 a0v = *(const float4*)(r0+j); w0[j]=a0v.x; w0[j+1]=a0v.y; w0[j+2]=a0v.z; w0[j+3]=a0v.w;
      float4 a1v = *(const float4*)(r1+j); w1[j]=a1v.x; w1[j+1]=a1v.y; w1[j+2]=a1v.z; w1[j+3]=a1v.w;
      float4 a2v = *(const float4*)(r2+j); w2[j]=a2v.x; w2[j+1]=a2v.y; w2[j+2]=a2v.z; w2[j+3]=a2v.w;
      float4 a3v = *(const float4*)(r3+j); w3[j]=a3v.x; w3[j+1]=a3v.y; w3[j+2]=a3v.z; w3[j+3]=a3v.w;
    }
  }
  const float wih0=Wih[l], wih1=Wih[Hn+l], wih2=Wih[2*Hn+l], wih3=Wih[3*Hn+l];
  const float b0=bia[l], b1=bia[Hn+l], b2=bia[2*Hn+l], b3=bia[3*Hn+l];
  const float* xp = x + bi*Tn*Fn + f;
  const float xrA = xp[l*Fn];           // x_t for t = lane
  const float xrB = xp[(Hn+l)*Fn];      // x_t for t = 64+lane
  float h=0.f, c=0.f;
  #pragma unroll 1
  for (int t=0;t<Tn;++t){
    const float xt = rlane(t<Hn ? xrA : xrB, t & (Hn-1));
    float a0 = b0 + xt*wih0;
    float a1 = b1 + xt*wih1;
    float a2 = b2 + xt*wih2;
    float a3 = b3 + xt*wih3;
    #pragma unroll
    for (int j=0;j<Hn;++j){
      const float hj = rlane(h, j);
      a0 += hj*w0[j]; a1 += hj*w1[j]; a2 += hj*w2[j]; a3 += hj*w3[j];
    }
    c = sigf(a1)*c + sigf(a0)*tanhfast(a2);
    h = sigf(a3)*tanhfast(c);
  }
  outp[inst*Hn + l] = h;
}

// ---------------- Stage B1: feature attention softmax (writes output b) ----------------
// grid 640 (= bi*40+i), block 64
__global__ __launch_bounds__(64) void k_featattn(
    const float* __restrict__ hq, const float* __restrict__ hk, const float* __restrict__ hv,
    float* __restrict__ Wsm, float* __restrict__ out_b)
{
  const int blk = blockIdx.x;
  const int bi = blk / Fn, i = blk % Fn;
  const int j = threadIdx.x;
  __shared__ float qrow[Hn];
  qrow[j] = hq[blk*Hn + j];
  __syncthreads();
  float s = -1e30f;
  if (j < Fn){
    const float* krow = hk + (bi*Fn + j)*Hn;
    float a = 0.f;
    #pragma unroll
    for (int h2=0; h2<Hn; ++h2) a += qrow[h2]*krow[h2];
    s = a * 0.125f * hv[bi*Fn + j];   // /sqrt(64) * V
  }
  float m = s;
  #pragma unroll
  for (int off=32; off>0; off>>=1) m = fmaxf(m, __shfl_xor(m, off));
  float e = (j < Fn) ? __expf(s - m) : 0.f;
  float tot = e;
  #pragma unroll
  for (int off=32; off>0; off>>=1) tot += __shfl_xor(tot, off);
  float p = e / tot;
  if (j < Fn){
    Wsm[blk*Fn + j] = p;
    out_b[bi*(Fn*Fn) + j*Fn + i] = p;   // b = Wsm.transpose(0,2,1)
  }
}

// ---------------- Stage B2: attn_output + src concat ----------------
// grid 2048 (= bi*128+t), block 128
__global__ __launch_bounds__(128) void k_build_src(
    const float* __restrict__ x, const float* __restrict__ Wsm, float* __restrict__ src)
{
  const int blk = blockIdx.x;
  const int bi = blk / Tn;
  const int tid = threadIdx.x;
  __shared__ float xrow[Fn];
  if (tid < Fn) xrow[tid] = x[blk*Fn + tid];
  __syncthreads();
  if (tid < Fn){
    src[blk*Dn + tid] = xrow[tid];
  } else if (tid < Dn){
    const int i = tid - Fn;
    const float* wrow = Wsm + (bi*Fn + i)*Fn;
    float a = 0.f;
    #pragma unroll
    for (int j2=0;j2<Fn;++j2) a += xrow[j2]*wrow[j2];
    src[blk*Dn + tid] = a;
  }
}

// ---------------- Transformer: qkv projection (group shuffle; k,v from q!) ----------------
// grid 2048, block 128
__global__ __launch_bounds__(128) void k_qkv(
    const float* __restrict__ src,
    const float* __restrict__ Wq, const float* __restrict__ bq,
    const float* __restrict__ Wk, const float* __restrict__ bk,
    const float* __restrict__ Wv, const float* __restrict__ bv,
    float* __restrict__ q, float* __restrict__ k, float* __restrict__ v)
{
  const int row = blockIdx.x;
  const int t = threadIdx.x;
  __shared__ float qs[Dn];
  __shared__ float qrow[Dn];
  if (t < Dn) qs[t] = src[row*Dn + (t%5)*16 + t/5];   // channel shuffle
  __syncthreads();
  if (t < Dn){
    const float* wr = Wq + t*Dn;
    float a = bq[t];
    #pragma unroll 8
    for (int d2=0; d2<Dn; ++d2) a += qs[d2]*wr[d2];
    qrow[t] = a;
    q[row*Dn + t] = a;
  }
  __syncthreads();
  if (t < Dn){
    const float* wk = Wk + t*Dn;
    const float* wv = Wv + t*Dn;
    float ak = bk[t], av = bv[t];
    #pragma unroll 8
    for (int d2=0; d2<Dn; ++d2){ float qq = qrow[d2]; ak += qq*wk[d2]; av += qq*wv[d2]; }
    k[row*Dn + t] = ak;
    v[row*Dn + t] = av;
  }
}

// ---------------- Transformer: attention per (s1,h,bi); writes output c ----------------
// grid (128, 5, 16), block 128
__global__ __launch_bounds__(128) void k_attn(
    const float* __restrict__ q, const float* __restrict__ k, const float* __restrict__ v,
    float* __restrict__ o, float* __restrict__ c_out)
{
  const int s1 = blockIdx.x, h = blockIdx.y, bi = blockIdx.z;
  const int s2 = threadIdx.x;
  __shared__ float qf[DKn];
  __shared__ float p[Tn];
  __shared__ float red_m[2];
  __shared__ float red_s[2];
  if (s2 < DKn) qf[s2] = q[(bi*Tn + s1)*Dn + h*DKn + s2];
  __syncthreads();
  const float* krow = k + (bi*Tn + s2)*Dn + h*DKn;
  float a = 0.f;
  #pragma unroll
  for (int d2=0; d2<DKn; ++d2) a += qf[d2]*krow[d2];
  a *= 0.25f;  // 1/sqrt(16)
  const int wv_id = s2 >> 6;
  float m = a;
  #pragma unroll
  for (int off=32; off>0; off>>=1) m = fmaxf(m, __shfl_xor(m, off));
  if ((s2 & 63) == 0) red_m[wv_id] = m;
  __syncthreads();
  m = fmaxf(red_m[0], red_m[1]);
  float e = __expf(a - m);
  float tot = e;
  #pragma unroll
  for (int off=32; off>0; off>>=1) tot += __shfl_xor(tot, off);
  if ((s2 & 63) == 0) red_s[wv_id] = tot;
  __syncthreads();
  tot = red_s[0] + red_s[1];
  float pv = e / tot;
  p[s2] = pv;
  c_out[((bi*NHn + h)*Tn + s1)*Tn + s2] = pv;
  __syncthreads();
  if (s2 < DKn){
    const float* vcol = v + bi*Tn*Dn + h*DKn + s2;
    float acc = 0.f;
    for (int j2=0;j2<Tn;++j2) acc += p[j2]*vcol[j2*Dn];
    o[(bi*Tn + s1)*Dn + h*DKn + s2] = acc;
  }
}

// ---------------- Transformer: Wo + residual + LayerNorm ----------------
// grid 2048, block 128
__global__ __launch_bounds__(128) void k_o_ln(
    const float* __restrict__ o, const float* __restrict__ Wo, const float* __restrict__ bo,
    const float* __restrict__ lng, const float* __restrict__ lnb, float* __restrict__ src)
{
  const int row = blockIdx.x;
  const int t = threadIdx.x;
  __shared__ float orow[Dn];
  __shared__ float red[128];
  if (t < Dn) orow[t] = o[row*Dn + t];
  __syncthreads();
  float val = 0.f;
  if (t < Dn){
    const float* wr = Wo + t*Dn;
    float a = bo[t];
    #pragma unroll 8
    for (int d2=0; d2<Dn; ++d2) a += orow[d2]*wr[d2];
    val = a + src[row*Dn + t];
  }
  red[t] = (t < Dn) ? val : 0.f;
  __syncthreads();
  for (int s=64; s>0; s>>=1){ if (t < s) red[t] += red[t+s]; __syncthreads(); }
  const float mean = red[0] * (1.f/Dn);
  __syncthreads();
  float dv = (t < Dn) ? (val - mean) : 0.f;
  red[t] = dv*dv;
  __syncthreads();
  for (int s=64; s>0; s>>=1){ if (t < s) red[t] += red[t+s]; __syncthreads(); }
  const float rstd = rsqrtf(red[0]*(1.f/Dn) + 1e-5f);
  if (t < Dn) src[row*Dn + t] = (val - mean)*rstd*lng[t] + lnb[t];
}

// ---------------- Transformer: FF + residual + LayerNorm ----------------
// grid 2048, block 320
__global__ __launch_bounds__(320) void k_ff_ln(
    const float* __restrict__ W1, const float* __restrict__ b1,
    const float* __restrict__ W2, const float* __restrict__ b2,
    const float* __restrict__ lng, const float* __restrict__ lnb, float* __restrict__ src)
{
  const int row = blockIdx.x;
  const int t = threadIdx.x;
  __shared__ float srow[Dn];
  __shared__ float h1[FFn];
  __shared__ float red[128];
  if (t < Dn) srow[t] = src[row*Dn + t];
  __syncthreads();
  {
    const float* wr = W1 + t*Dn;
    float a = b1[t];
    #pragma unroll 8
    for (int d2=0; d2<Dn; ++d2) a += srow[d2]*wr[d2];
    h1[t] = fmaxf(a, 0.f);
  }
  __syncthreads();
  float val = 0.f;
  if (t < Dn){
    const float* wr = W2 + t*FFn;
    float a = b2[t];
    #pragma unroll 8
    for (int d2=0; d2<FFn; ++d2) a += h1[d2]*wr[d2];
    val = a + srow[t];
  }
  if (t < 128) red[t] = (t < Dn) ? val : 0.f;
  __syncthreads();
  for (int s=64; s>0; s>>=1){ if (t < s) red[t] += red[t+s]; __syncthreads(); }
  const float mean = red[0] * (1.f/Dn);
  __syncthreads();
  if (t < 128){ float dv = (t < Dn) ? (val - mean) : 0.f; red[t] = dv*dv; }
  __syncthreads();
  for (int s=64; s>0; s>>=1){ if (t < s) red[t] += red[t+s]; __syncthreads(); }
  const float rstd = rsqrtf(red[0]*(1.f/Dn) + 1e-5f);
  if (t < Dn) src[row*Dn + t] = (val - mean)*rstd*lng[t] + lnb[t];
}

// ---------------- BiLSTM: parallel input projection gx = X @ Wih.T + b ----------------
// grid (2048, 2), block 256
__global__ __launch_bounds__(256) void k_gx(
    const float* __restrict__ X, int inD,
    const float* __restrict__ WihF, const float* __restrict__ bF,
    const float* __restrict__ WihB, const float* __restrict__ bB,
    float* __restrict__ gx)
{
  const int row = blockIdx.x;      // n*128 + t
  const int dir = blockIdx.y;
  const int g = threadIdx.x;
  __shared__ float xs[128];
  for (int d2=g; d2<inD; d2+=256) xs[d2] = X[row*inD + d2];
  __syncthreads();
  const float* W  = dir ? WihB : WihF;
  const float* bb = dir ? bB  : bF;
  const float* wr = W + g*inD;
  float a = bb[g];
  for (int d2=0; d2<inD; ++d2) a += xs[d2]*wr[d2];
  gx[dir*(Bn*Tn*256) + row*256 + g] = a;
}

// ---------------- BiLSTM: wave-per-(n,dir) recurrence, no barriers ----------------
// grid (16,2), block 64. out[n,t, dir*64 + l]
__global__ __launch_bounds__(64,1) void k_bilstm_rec_w(
    const float* __restrict__ gx,
    const float* __restrict__ WhhF, const float* __restrict__ WhhB,
    float* __restrict__ outp)
{
  const int n = blockIdx.x;
  const int dir = blockIdx.y;
  const int l = threadIdx.x;
  const float* Whh = dir ? WhhB : WhhF;
  float w0[Hn], w1[Hn], w2[Hn], w3[Hn];
  {
    const float* r0 = Whh + (0*Hn + l)*Hn;
    const float* r1 = Whh + (1*Hn + l)*Hn;
    const float* r2 = Whh + (2*Hn + l)*Hn;
    const float* r3 = Whh + (3*Hn + l)*Hn;
    #pragma unroll
    for (int j=0;j<Hn;j+=4){
      float4 a0v = *(const float4*)(r0+j); w0[j]=a0v.x; w0[j+1]=a0v.y; w0[j+2]=a0v.z; w0[j+3]=a0v.w;
      float4 a1v = *(const float4*)(r1+j); w1[j]=a1v.x; w1[j+1]=a1v.y; w1[j+2]=a1v.z; w1[j+3]=a1v.w;
      float4 a2v = *(const float4*)(r2+j); w2[j]=a2v.x; w2[j+1]=a2v.y; w2[j+2]=a2v.z; w2[j+3]=a2v.w;
      float4 a3v = *(const float4*)(r3+j); w3[j]=a3v.x; w3[j+1]=a3v.y; w3[j+2]=a3v.z; w3[j+3]=a3v.w;
    }
  }
  const float* gxd = gx + dir*(Bn*Tn*256) + n*Tn*256;
  float h=0.f, c=0.f;
  const int t0 = dir ? Tn-1 : 0;
  float g0 = gxd[t0*256 + l];
  float g1 = gxd[t0*256 + Hn + l];
  float g2 = gxd[t0*256 + 2*Hn + l];
  float g3 = gxd[t0*256 + 3*Hn + l];
  #pragma unroll 1
  for (int step=0; step<Tn; ++step){
    const int t = dir ? (Tn-1-step) : step;
    int tn = dir ? (Tn-2-step) : (step+1);
    tn = max(0, min(Tn-1, tn));
    // prefetch next step's gates (dup read on last step, value unused)
    const float n0 = gxd[tn*256 + l];
    const float n1 = gxd[tn*256 + Hn + l];
    const float n2 = gxd[tn*256 + 2*Hn + l];
    const float n3 = gxd[tn*256 + 3*Hn + l];
    float a0=g0, a1=g1, a2=g2, a3=g3;
    #pragma unroll
    for (int j=0;j<Hn;++j){
      const float hj = rlane(h, j);
      a0 += hj*w0[j]; a1 += hj*w1[j]; a2 += hj*w2[j]; a3 += hj*w3[j];
    }
    c = sigf(a1)*c + sigf(a0)*tanhfast(a2);
    h = sigf(a3)*tanhfast(c);
    outp[(n*Tn + t)*128 + dir*Hn + l] = h;
    g0=n0; g1=n1; g2=n2; g3=n3;
  }
}

// ---------------- Final: relu(last step) -> fc1 -> relu -> fc2 ----------------
// grid 16, block 128
__global__ __launch_bounds__(128) void k_final(
    const float* __restrict__ out1,
    const float* __restrict__ fc1W, const float* __restrict__ fc1b,
    const float* __restrict__ fc2W, const float* __restrict__ fc2b,
    float* __restrict__ outp)
{
  const int n = blockIdx.x;
  const int t = threadIdx.x;
  __shared__ float r[128];
  __shared__ float a1[64];
  r[t] = fmaxf(out1[(n*Tn + (Tn-1))*128 + t], 0.f);
  __syncthreads();
  if (t < 64){
    const float* wr = fc1W + t*128;
    float a = fc1b[t];
    #pragma unroll 8
    for (int d2=0; d2<128; ++d2) a += r[d2]*wr[d2];
    a1[t] = fmaxf(a, 0.f);
  }
  __syncthreads();
  if (t == 0){
    float a = fc2b[0];
    #pragma unroll 8
    for (int d2=0; d2<64; ++d2) a += a1[d2]*fc2W[d2];
    outp[n] = a;
  }
}

extern "C" void kernel_launch(void* const* d_in, const int* in_sizes, int n_in,
                              void* d_out, int out_size, void* d_ws, size_t ws_size,
                              hipStream_t stream)
{
  const float* x     = (const float*)d_in[0];
  const float* qWih  = (const float*)d_in[1];
  const float* qWhh  = (const float*)d_in[2];
  const float* qb    = (const float*)d_in[3];
  const float* kWih  = (const float*)d_in[4];
  const float* kWhh  = (const float*)d_in[5];
  const float* kb    = (const float*)d_in[6];
  const float* vWih  = (const float*)d_in[7];
  const float* vWhh  = (const float*)d_in[8];
  const float* vb    = (const float*)d_in[9];
  const float* tWq   = (const float*)d_in[10];
  const float* tbq   = (const float*)d_in[11];
  const float* tWk   = (const float*)d_in[12];
  const float* tbk   = (const float*)d_in[13];
  const float* tWv   = (const float*)d_in[14];
  const float* tbv   = (const float*)d_in[15];
  const float* tWo   = (const float*)d_in[16];
  const float* tbo   = (const float*)d_in[17];
  const float* tW1   = (const float*)d_in[18];
  const float* tb1   = (const float*)d_in[19];
  const float* tW2   = (const float*)d_in[20];
  const float* tb2   = (const float*)d_in[21];
  const float* tlng  = (const float*)d_in[22];
  const float* tlnb  = (const float*)d_in[23];
  const float* l0fWih= (const float*)d_in[24];
  const float* l0fWhh= (const float*)d_in[25];
  const float* l0fb  = (const float*)d_in[26];
  const float* l0bWih= (const float*)d_in[27];
  const float* l0bWhh= (const float*)d_in[28];
  const float* l0bb  = (const float*)d_in[29];
  const float* l1fWih= (const float*)d_in[30];
  const float* l1fWhh= (const float*)d_in[31];
  const float* l1fb  = (const float*)d_in[32];
  const float* l1bWih= (const float*)d_in[33];
  const float* l1bWhh= (const float*)d_in[34];
  const float* l1bb  = (const float*)d_in[35];
  const float* fc1W  = (const float*)d_in[36];
  const float* fc1b  = (const float*)d_in[37];
  const float* fc2W  = (const float*)d_in[38];
  const float* fc2b  = (const float*)d_in[39];

  // fp32 workspace, no aliasing, total 2,500,224 floats = 9.54 MB
  float* ws  = (float*)d_ws;
  float* hq  = ws;                      // 40960
  float* hk  = hq  + 640*64;            // 40960
  float* hv  = hk  + 640*64;            // 640
  float* Wsm = hv  + 640;               // 25600
  float* src = Wsm + 16*40*40;          // 163840
  float* q   = src + 16*128*80;
  float* k   = q   + 16*128*80;
  float* v   = k   + 16*128*80;
  float* o   = v   + 16*128*80;
  float* gx  = o   + 16*128*80;         // 2 * 16*128*256 = 1048576
  float* lout0 = gx + 2*16*128*256;     // 262144
  float* lout1 = lout0 + 16*128*128;    // 262144

  float* outp  = (float*)d_out;            // [16] (out [B,1])
  float* out_b = outp + 16;                // [16,40,40]
  float* out_c = out_b + 16*40*40;         // [2,16,5,128,128]

  // Stage A: per-feature LSTMs (wave-per-instance)
  k_feat_lstm_w<<<1290, 64, 0, stream>>>(x, qWih,qWhh,qb, kWih,kWhh,kb, vWih,vWhh,vb, hq,hk,hv);
  // Stage B
  k_featattn<<<640, 64, 0, stream>>>(hq, hk, hv, Wsm, out_b);
  k_build_src<<<2048, 128, 0, stream>>>(x, Wsm, src);
  // Transformer layers
  for (int l=0; l<2; ++l){
    k_qkv<<<2048, 128, 0, stream>>>(src, tWq + l*Dn*Dn, tbq + l*Dn,
                                    tWk + l*Dn*Dn, tbk + l*Dn,
                                    tWv + l*Dn*Dn, tbv + l*Dn, q, k, v);
    k_attn<<<dim3(128,5,16), 128, 0, stream>>>(q, k, v, o, out_c + (size_t)l*16*5*128*128);
    k_o_ln<<<2048, 128, 0, stream>>>(o, tWo + l*Dn*Dn, tbo + l*Dn, tlng + l*Dn, tlnb + l*Dn, src);
    k_ff_ln<<<2048, 320, 0, stream>>>(tW1 + l*FFn*Dn, tb1 + l*FFn, tW2 + l*Dn*FFn, tb2 + l*Dn,
                                      tlng + l*Dn, tlnb + l*Dn, src);
  }
  // BiLSTM layer 0 (inD=80)
  k_gx<<<dim3(2048,2), 256, 0, stream>>>(src, 80, l0fWih, l0fb, l0bWih, l0bb, gx);
  k_bilstm_rec_w<<<dim3(16,2), 64, 0, stream>>>(gx, l0fWhh, l0bWhh, lout0);
  // BiLSTM layer 1 (inD=128)
  k_gx<<<dim3(2048,2), 256, 0, stream>>>(lout0, 128, l1fWih, l1fb, l1bWih, l1bb, gx);
  k_bilstm_rec_w<<<dim3(16,2), 64, 0, stream>>>(gx, l1fWhh, l1bWhh, lout1);
  // Final head
  k_final<<<16, 128, 0, stream>>>(lout1, fc1W, fc1b, fc2W, fc2b, outp);
}

// Round 6
// 816.327 us; speedup vs baseline: 1.2123x; 1.2123x over previous
//
#include <hip/hip_runtime.h>

__device__ __forceinline__ float sigf(float x){ return 1.0f/(1.0f+__expf(-x)); }
__device__ __forceinline__ float tanhfast(float x){ return 1.0f - 2.0f/(__expf(2.0f*x)+1.0f); }

#define Bn 16
#define Tn 128
#define Fn 40
#define Hn 64
#define Dn 80   // 2F
#define NHn 5
#define DKn 16
#define FFn 320

// Load 64-float weight row into VGPR-pinned array
#define LOAD_PIN_ROW(dst, srcp)                                        \
  {                                                                    \
    _Pragma("unroll")                                                  \
    for (int jj=0; jj<16; ++jj){                                       \
      float4 tv = *(const float4*)((srcp) + 4*jj);                     \
      dst[4*jj]=tv.x; dst[4*jj+1]=tv.y; dst[4*jj+2]=tv.z; dst[4*jj+3]=tv.w; \
    }                                                                  \
    _Pragma("unroll")                                                  \
    for (int jj=0; jj<64; ++jj){ asm volatile("" : "+v"(dst[jj])); }   \
  }

// ---------------- Stage A: per-feature LSTMs (q,k,v) ----------------
// grid 1285 x 128. blk<640: q inst=blk; 640<=blk<1280: k inst=blk-640; blk>=1280: v lane-parallel.
// 2-wave block, thread l handles gate rows {l, l+128}; threads<64 own h[l],c[l].
__global__ __launch_bounds__(128,1) void k_feat_lstm2(
    const float* __restrict__ x,
    const float* __restrict__ qWih, const float* __restrict__ qWhh, const float* __restrict__ qb,
    const float* __restrict__ kWih, const float* __restrict__ kWhh, const float* __restrict__ kb,
    const float* __restrict__ vWih, const float* __restrict__ vWhh, const float* __restrict__ vb,
    float* __restrict__ hq, float* __restrict__ hk, float* __restrict__ hv)
{
  const int blk = blockIdx.x;
  const int l = threadIdx.x;
  if (blk >= 1280){
    const int inst = (blk - 1280)*128 + l;      // 0..639
    const int bi = inst/Fn, f = inst%Fn;
    const float* xp = x + bi*Tn*Fn + f;
    const float wih0=vWih[0], wih1=vWih[1], wih2=vWih[2], wih3=vWih[3];
    const float u0=vWhh[0], u1=vWhh[1], u2=vWhh[2], u3=vWhh[3];
    const float c0=vb[0], c1=vb[1], c2=vb[2], c3=vb[3];
    float h=0.f, c=0.f;
    #pragma unroll 1
    for (int t=0;t<Tn;++t){
      float xt = xp[t*Fn];
      float zi = xt*wih0 + h*u0 + c0;
      float zf = xt*wih1 + h*u1 + c1;
      float zg = xt*wih2 + h*u2 + c2;
      float zo = xt*wih3 + h*u3 + c3;
      c = sigf(zf)*c + sigf(zi)*tanhfast(zg);
      h = sigf(zo)*tanhfast(c);
    }
    hv[inst] = h;
    return;
  }
  const bool isk = blk >= 640;
  const int inst = isk ? blk-640 : blk;         // 0..639
  const int bi = inst/Fn, f = inst%Fn;
  const float* Whh = isk ? kWhh : qWhh;
  const float* Wih = isk ? kWih : qWih;
  const float* bia = isk ? kb  : qb;
  float* outp = isk ? hk : hq;

  const int r0 = l;        // i (l<64) or f (l>=64)
  const int r1 = l + 128;  // g (l<64) or o (l>=64)

  float w0[Hn], w1[Hn];
  LOAD_PIN_ROW(w0, Whh + r0*Hn);
  LOAD_PIN_ROW(w1, Whh + r1*Hn);
  const float wih0 = Wih[r0], wih1 = Wih[r1];
  const float bb0 = bia[r0], bb1 = bia[r1];

  __shared__ __align__(16) float hb[Hn];
  __shared__ float zb[4*Hn];
  __shared__ float xls[Tn];

  const float* xp = x + bi*Tn*Fn + f;
  xls[l] = xp[l*Fn];                    // stage all 128 timesteps
  if (l < Hn) hb[l] = 0.f;
  float c = 0.f, h = 0.f;
  __syncthreads();

  const float4* hb4 = (const float4*)hb;
  #pragma unroll 1
  for (int t=0;t<Tn;++t){
    const float xt = xls[t];
    float a0 = bb0 + xt*wih0;
    float a1 = bb1 + xt*wih1;
    #pragma unroll
    for (int jj=0; jj<16; ++jj){
      const float4 hv4 = hb4[jj];
      a0 += hv4.x*w0[4*jj  ] + hv4.y*w0[4*jj+1] + hv4.z*w0[4*jj+2] + hv4.w*w0[4*jj+3];
      a1 += hv4.x*w1[4*jj  ] + hv4.y*w1[4*jj+1] + hv4.z*w1[4*jj+2] + hv4.w*w1[4*jj+3];
    }
    if (l >= Hn){ zb[l] = a0; zb[l+128] = a1; }   // f-row, o-row
    __syncthreads();
    if (l < Hn){
      const float zi = a0, zg = a1;
      const float zf = zb[l+64], zo = zb[l+192];
      c = sigf(zf)*c + sigf(zi)*tanhfast(zg);
      h = sigf(zo)*tanhfast(c);
      hb[l] = h;
    }
    __syncthreads();
  }
  if (l < Hn) outp[inst*Hn + l] = h;
}

// ---------------- Stage B1: feature attention softmax (writes output b) ----------------
__global__ __launch_bounds__(64) void k_featattn(
    const float* __restrict__ hq, const float* __restrict__ hk, const float* __restrict__ hv,
    float* __restrict__ Wsm, float* __restrict__ out_b)
{
  const int blk = blockIdx.x;
  const int bi = blk / Fn, i = blk % Fn;
  const int j = threadIdx.x;
  __shared__ float qrow[Hn];
  qrow[j] = hq[blk*Hn + j];
  __syncthreads();
  float s = -1e30f;
  if (j < Fn){
    const float* krow = hk + (bi*Fn + j)*Hn;
    float a = 0.f;
    #pragma unroll
    for (int h2=0; h2<Hn; ++h2) a += qrow[h2]*krow[h2];
    s = a * 0.125f * hv[bi*Fn + j];
  }
  float m = s;
  #pragma unroll
  for (int off=32; off>0; off>>=1) m = fmaxf(m, __shfl_xor(m, off));
  float e = (j < Fn) ? __expf(s - m) : 0.f;
  float tot = e;
  #pragma unroll
  for (int off=32; off>0; off>>=1) tot += __shfl_xor(tot, off);
  float p = e / tot;
  if (j < Fn){
    Wsm[blk*Fn + j] = p;
    out_b[bi*(Fn*Fn) + j*Fn + i] = p;
  }
}

// ---------------- Stage B2: attn_output + src concat ----------------
__global__ __launch_bounds__(128) void k_build_src(
    const float* __restrict__ x, const float* __restrict__ Wsm, float* __restrict__ src)
{
  const int blk = blockIdx.x;
  const int bi = blk / Tn;
  const int tid = threadIdx.x;
  __shared__ float xrow[Fn];
  if (tid < Fn) xrow[tid] = x[blk*Fn + tid];
  __syncthreads();
  if (tid < Fn){
    src[blk*Dn + tid] = xrow[tid];
  } else if (tid < Dn){
    const int i = tid - Fn;
    const float* wrow = Wsm + (bi*Fn + i)*Fn;
    float a = 0.f;
    #pragma unroll
    for (int j2=0;j2<Fn;++j2) a += xrow[j2]*wrow[j2];
    src[blk*Dn + tid] = a;
  }
}

// ---------------- Transformer: qkv projection ----------------
__global__ __launch_bounds__(128) void k_qkv(
    const float* __restrict__ src,
    const float* __restrict__ Wq, const float* __restrict__ bq,
    const float* __restrict__ Wk, const float* __restrict__ bk,
    const float* __restrict__ Wv, const float* __restrict__ bv,
    float* __restrict__ q, float* __restrict__ k, float* __restrict__ v)
{
  const int row = blockIdx.x;
  const int t = threadIdx.x;
  __shared__ float qs[Dn];
  __shared__ float qrow[Dn];
  if (t < Dn) qs[t] = src[row*Dn + (t%5)*16 + t/5];
  __syncthreads();
  if (t < Dn){
    const float* wr = Wq + t*Dn;
    float a = bq[t];
    #pragma unroll 8
    for (int d2=0; d2<Dn; ++d2) a += qs[d2]*wr[d2];
    qrow[t] = a;
    q[row*Dn + t] = a;
  }
  __syncthreads();
  if (t < Dn){
    const float* wk = Wk + t*Dn;
    const float* wv = Wv + t*Dn;
    float ak = bk[t], av = bv[t];
    #pragma unroll 8
    for (int d2=0; d2<Dn; ++d2){ float qq = qrow[d2]; ak += qq*wk[d2]; av += qq*wv[d2]; }
    k[row*Dn + t] = ak;
    v[row*Dn + t] = av;
  }
}

// ---------------- Transformer: attention ----------------
__global__ __launch_bounds__(128) void k_attn(
    const float* __restrict__ q, const float* __restrict__ k, const float* __restrict__ v,
    float* __restrict__ o, float* __restrict__ c_out)
{
  const int s1 = blockIdx.x, h = blockIdx.y, bi = blockIdx.z;
  const int s2 = threadIdx.x;
  __shared__ float qf[DKn];
  __shared__ float p[Tn];
  __shared__ float red_m[2];
  __shared__ float red_s[2];
  if (s2 < DKn) qf[s2] = q[(bi*Tn + s1)*Dn + h*DKn + s2];
  __syncthreads();
  const float* krow = k + (bi*Tn + s2)*Dn + h*DKn;
  float a = 0.f;
  #pragma unroll
  for (int d2=0; d2<DKn; ++d2) a += qf[d2]*krow[d2];
  a *= 0.25f;
  const int wv_id = s2 >> 6;
  float m = a;
  #pragma unroll
  for (int off=32; off>0; off>>=1) m = fmaxf(m, __shfl_xor(m, off));
  if ((s2 & 63) == 0) red_m[wv_id] = m;
  __syncthreads();
  m = fmaxf(red_m[0], red_m[1]);
  float e = __expf(a - m);
  float tot = e;
  #pragma unroll
  for (int off=32; off>0; off>>=1) tot += __shfl_xor(tot, off);
  if ((s2 & 63) == 0) red_s[wv_id] = tot;
  __syncthreads();
  tot = red_s[0] + red_s[1];
  float pv = e / tot;
  p[s2] = pv;
  c_out[((bi*NHn + h)*Tn + s1)*Tn + s2] = pv;
  __syncthreads();
  if (s2 < DKn){
    const float* vcol = v + bi*Tn*Dn + h*DKn + s2;
    float acc = 0.f;
    for (int j2=0;j2<Tn;++j2) acc += p[j2]*vcol[j2*Dn];
    o[(bi*Tn + s1)*Dn + h*DKn + s2] = acc;
  }
}

// ---------------- Transformer: Wo + residual + LayerNorm ----------------
__global__ __launch_bounds__(128) void k_o_ln(
    const float* __restrict__ o, const float* __restrict__ Wo, const float* __restrict__ bo,
    const float* __restrict__ lng, const float* __restrict__ lnb, float* __restrict__ src)
{
  const int row = blockIdx.x;
  const int t = threadIdx.x;
  __shared__ float orow[Dn];
  __shared__ float red[128];
  if (t < Dn) orow[t] = o[row*Dn + t];
  __syncthreads();
  float val = 0.f;
  if (t < Dn){
    const float* wr = Wo + t*Dn;
    float a = bo[t];
    #pragma unroll 8
    for (int d2=0; d2<Dn; ++d2) a += orow[d2]*wr[d2];
    val = a + src[row*Dn + t];
  }
  red[t] = (t < Dn) ? val : 0.f;
  __syncthreads();
  for (int s=64; s>0; s>>=1){ if (t < s) red[t] += red[t+s]; __syncthreads(); }
  const float mean = red[0] * (1.f/Dn);
  __syncthreads();
  float dv = (t < Dn) ? (val - mean) : 0.f;
  red[t] = dv*dv;
  __syncthreads();
  for (int s=64; s>0; s>>=1){ if (t < s) red[t] += red[t+s]; __syncthreads(); }
  const float rstd = rsqrtf(red[0]*(1.f/Dn) + 1e-5f);
  if (t < Dn) src[row*Dn + t] = (val - mean)*rstd*lng[t] + lnb[t];
}

// ---------------- Transformer: FF + residual + LayerNorm ----------------
__global__ __launch_bounds__(320) void k_ff_ln(
    const float* __restrict__ W1, const float* __restrict__ b1,
    const float* __restrict__ W2, const float* __restrict__ b2,
    const float* __restrict__ lng, const float* __restrict__ lnb, float* __restrict__ src)
{
  const int row = blockIdx.x;
  const int t = threadIdx.x;
  __shared__ float srow[Dn];
  __shared__ float h1[FFn];
  __shared__ float red[128];
  if (t < Dn) srow[t] = src[row*Dn + t];
  __syncthreads();
  {
    const float* wr = W1 + t*Dn;
    float a = b1[t];
    #pragma unroll 8
    for (int d2=0; d2<Dn; ++d2) a += srow[d2]*wr[d2];
    h1[t] = fmaxf(a, 0.f);
  }
  __syncthreads();
  float val = 0.f;
  if (t < Dn){
    const float* wr = W2 + t*FFn;
    float a = b2[t];
    #pragma unroll 8
    for (int d2=0; d2<FFn; ++d2) a += h1[d2]*wr[d2];
    val = a + srow[t];
  }
  if (t < 128) red[t] = (t < Dn) ? val : 0.f;
  __syncthreads();
  for (int s=64; s>0; s>>=1){ if (t < s) red[t] += red[t+s]; __syncthreads(); }
  const float mean = red[0] * (1.f/Dn);
  __syncthreads();
  if (t < 128){ float dv = (t < Dn) ? (val - mean) : 0.f; red[t] = dv*dv; }
  __syncthreads();
  for (int s=64; s>0; s>>=1){ if (t < s) red[t] += red[t+s]; __syncthreads(); }
  const float rstd = rsqrtf(red[0]*(1.f/Dn) + 1e-5f);
  if (t < Dn) src[row*Dn + t] = (val - mean)*rstd*lng[t] + lnb[t];
}

// ---------------- BiLSTM: parallel input projection gx = X @ Wih.T + b ----------------
__global__ __launch_bounds__(256) void k_gx(
    const float* __restrict__ X, int inD,
    const float* __restrict__ WihF, const float* __restrict__ bF,
    const float* __restrict__ WihB, const float* __restrict__ bB,
    float* __restrict__ gx)
{
  const int row = blockIdx.x;
  const int dir = blockIdx.y;
  const int g = threadIdx.x;
  __shared__ float xs[128];
  for (int d2=g; d2<inD; d2+=256) xs[d2] = X[row*inD + d2];
  __syncthreads();
  const float* W  = dir ? WihB : WihF;
  const float* bb = dir ? bB  : bF;
  const float* wr = W + g*inD;
  float a = bb[g];
  for (int d2=0; d2<inD; ++d2) a += xs[d2]*wr[d2];
  gx[dir*(Bn*Tn*256) + row*256 + g] = a;
}

// ---------------- BiLSTM recurrence: 2-wave block, 2 rows/thread, pinned weights ----------------
// grid (16,2), block 128. out[n,t, dir*64 + l]
__global__ __launch_bounds__(128,1) void k_bilstm_rec2(
    const float* __restrict__ gx,
    const float* __restrict__ WhhF, const float* __restrict__ WhhB,
    float* __restrict__ outp)
{
  const int n = blockIdx.x;
  const int dir = blockIdx.y;
  const int l = threadIdx.x;
  const float* Whh = dir ? WhhB : WhhF;
  const int r0 = l, r1 = l + 128;
  float w0[Hn], w1[Hn];
  LOAD_PIN_ROW(w0, Whh + r0*Hn);
  LOAD_PIN_ROW(w1, Whh + r1*Hn);

  __shared__ __align__(16) float hb[Hn];
  __shared__ float zb[4*Hn];
  if (l < Hn) hb[l] = 0.f;
  float c = 0.f, h = 0.f;
  __syncthreads();

  const float* gxd = gx + dir*(Bn*Tn*256) + n*Tn*256;
  const float4* hb4 = (const float4*)hb;
  const int t0 = dir ? Tn-1 : 0;
  float g0 = gxd[t0*256 + r0];
  float g1 = gxd[t0*256 + r1];
  #pragma unroll 1
  for (int step=0; step<Tn; ++step){
    const int t = dir ? (Tn-1-step) : step;
    int tn = dir ? (Tn-2-step) : (step+1);
    tn = max(0, min(Tn-1, tn));
    const float p0 = gxd[tn*256 + r0];   // prefetch next step
    const float p1 = gxd[tn*256 + r1];
    float a0 = g0, a1 = g1;
    #pragma unroll
    for (int jj=0; jj<16; ++jj){
      const float4 hv4 = hb4[jj];
      a0 += hv4.x*w0[4*jj  ] + hv4.y*w0[4*jj+1] + hv4.z*w0[4*jj+2] + hv4.w*w0[4*jj+3];
      a1 += hv4.x*w1[4*jj  ] + hv4.y*w1[4*jj+1] + hv4.z*w1[4*jj+2] + hv4.w*w1[4*jj+3];
    }
    if (l >= Hn){ zb[l] = a0; zb[l+128] = a1; }
    __syncthreads();
    if (l < Hn){
      const float zi = a0, zg = a1;
      const float zf = zb[l+64], zo = zb[l+192];
      c = sigf(zf)*c + sigf(zi)*tanhfast(zg);
      h = sigf(zo)*tanhfast(c);
      hb[l] = h;
      outp[(n*Tn + t)*128 + dir*Hn + l] = h;
    }
    __syncthreads();
    g0 = p0; g1 = p1;
  }
}

// ---------------- Final head ----------------
__global__ __launch_bounds__(128) void k_final(
    const float* __restrict__ out1,
    const float* __restrict__ fc1W, const float* __restrict__ fc1b,
    const float* __restrict__ fc2W, const float* __restrict__ fc2b,
    float* __restrict__ outp)
{
  const int n = blockIdx.x;
  const int t = threadIdx.x;
  __shared__ float r[128];
  __shared__ float a1[64];
  r[t] = fmaxf(out1[(n*Tn + (Tn-1))*128 + t], 0.f);
  __syncthreads();
  if (t < 64){
    const float* wr = fc1W + t*128;
    float a = fc1b[t];
    #pragma unroll 8
    for (int d2=0; d2<128; ++d2) a += r[d2]*wr[d2];
    a1[t] = fmaxf(a, 0.f);
  }
  __syncthreads();
  if (t == 0){
    float a = fc2b[0];
    #pragma unroll 8
    for (int d2=0; d2<64; ++d2) a += a1[d2]*fc2W[d2];
    outp[n] = a;
  }
}

extern "C" void kernel_launch(void* const* d_in, const int* in_sizes, int n_in,
                              void* d_out, int out_size, void* d_ws, size_t ws_size,
                              hipStream_t stream)
{
  const float* x     = (const float*)d_in[0];
  const float* qWih  = (const float*)d_in[1];
  const float* qWhh  = (const float*)d_in[2];
  const float* qb    = (const float*)d_in[3];
  const float* kWih  = (const float*)d_in[4];
  const float* kWhh  = (const float*)d_in[5];
  const float* kb    = (const float*)d_in[6];
  const float* vWih  = (const float*)d_in[7];
  const float* vWhh  = (const float*)d_in[8];
  const float* vb    = (const float*)d_in[9];
  const float* tWq   = (const float*)d_in[10];
  const float* tbq   = (const float*)d_in[11];
  const float* tWk   = (const float*)d_in[12];
  const float* tbk   = (const float*)d_in[13];
  const float* tWv   = (const float*)d_in[14];
  const float* tbv   = (const float*)d_in[15];
  const float* tWo   = (const float*)d_in[16];
  const float* tbo   = (const float*)d_in[17];
  const float* tW1   = (const float*)d_in[18];
  const float* tb1   = (const float*)d_in[19];
  const float* tW2   = (const float*)d_in[20];
  const float* tb2   = (const float*)d_in[21];
  const float* tlng  = (const float*)d_in[22];
  const float* tlnb  = (const float*)d_in[23];
  const float* l0fWih= (const float*)d_in[24];
  const float* l0fWhh= (const float*)d_in[25];
  const float* l0fb  = (const float*)d_in[26];
  const float* l0bWih= (const float*)d_in[27];
  const float* l0bWhh= (const float*)d_in[28];
  const float* l0bb  = (const float*)d_in[29];
  const float* l1fWih= (const float*)d_in[30];
  const float* l1fWhh= (const float*)d_in[31];
  const float* l1fb  = (const float*)d_in[32];
  const float* l1bWih= (const float*)d_in[33];
  const float* l1bWhh= (const float*)d_in[34];
  const float* l1bb  = (const float*)d_in[35];
  const float* fc1W  = (const float*)d_in[36];
  const float* fc1b  = (const float*)d_in[37];
  const float* fc2W  = (const float*)d_in[38];
  const float* fc2b  = (const float*)d_in[39];

  float* ws  = (float*)d_ws;
  float* hq  = ws;
  float* hk  = hq  + 640*64;
  float* hv  = hk  + 640*64;
  float* Wsm = hv  + 640;
  float* src = Wsm + 16*40*40;
  float* q   = src + 16*128*80;
  float* k   = q   + 16*128*80;
  float* v   = k   + 16*128*80;
  float* o   = v   + 16*128*80;
  float* gx  = o   + 16*128*80;
  float* lout0 = gx + 2*16*128*256;
  float* lout1 = lout0 + 16*128*128;

  float* outp  = (float*)d_out;
  float* out_b = outp + 16;
  float* out_c = out_b + 16*40*40;

  k_feat_lstm2<<<1285, 128, 0, stream>>>(x, qWih,qWhh,qb, kWih,kWhh,kb, vWih,vWhh,vb, hq,hk,hv);
  k_featattn<<<640, 64, 0, stream>>>(hq, hk, hv, Wsm, out_b);
  k_build_src<<<2048, 128, 0, stream>>>(x, Wsm, src);
  for (int l=0; l<2; ++l){
    k_qkv<<<2048, 128, 0, stream>>>(src, tWq + l*Dn*Dn, tbq + l*Dn,
                                    tWk + l*Dn*Dn, tbk + l*Dn,
                                    tWv + l*Dn*Dn, tbv + l*Dn, q, k, v);
    k_attn<<<dim3(128,5,16), 128, 0, stream>>>(q, k, v, o, out_c + (size_t)l*16*5*128*128);
    k_o_ln<<<2048, 128, 0, stream>>>(o, tWo + l*Dn*Dn, tbo + l*Dn, tlng + l*Dn, tlnb + l*Dn, src);
    k_ff_ln<<<2048, 320, 0, stream>>>(tW1 + l*FFn*Dn, tb1 + l*FFn, tW2 + l*Dn*FFn, tb2 + l*Dn,
                                      tlng + l*Dn, tlnb + l*Dn, src);
  }
  k_gx<<<dim3(2048,2), 256, 0, stream>>>(src, 80, l0fWih, l0fb, l0bWih, l0bb, gx);
  k_bilstm_rec2<<<dim3(16,2), 128, 0, stream>>>(gx, l0fWhh, l0bWhh, lout0);
  k_gx<<<dim3(2048,2), 256, 0, stream>>>(lout0, 128, l1fWih, l1fb, l1bWih, l1bb, gx);
  k_bilstm_rec2<<<dim3(16,2), 128, 0, stream>>>(gx, l1fWhh, l1bWhh, lout1);
  k_final<<<16, 128, 0, stream>>>(lout1, fc1W, fc1b, fc2W, fc2b, outp);
}